// Round 5
// baseline (122.823 us; speedup 1.0000x reference)
//
#include <hip/hip_runtime.h>
#include <math.h>

#define B_   8
#define N_   2048
#define IN_  256
#define H_   4
#define D_   64
#define C_   256            // H_*D_
#define M_   (B_*N_)        // 16384
#define NEG  0.2f
#define LOG2E 1.4426950408889634f

typedef short bf16x8 __attribute__((ext_vector_type(8)));
typedef float f32x4  __attribute__((ext_vector_type(4)));

// gfx950 packed f32->bf16 (RNE), src0 -> low half, src1 -> high half.
__device__ inline uint cvt_pk_bf16(float lo, float hi) {
    uint r;
    asm("v_cvt_pk_bf16_f32 %0, %1, %2" : "=v"(r) : "v"(lo), "v"(hi));
    return r;
}

// cast 8 f32 -> bf16x8 (RNE) via 4x v_cvt_pk_bf16_f32.
__device__ inline bf16x8 cast8(const float v[8]) {
    union { bf16x8 v; uint u[4]; } H;
    #pragma unroll
    for (int j = 0; j < 4; j++)
        H.u[j] = cvt_pk_bf16(v[2 * j], v[2 * j + 1]);
    return H.v;
}

// ---------------------------------------------------------------------------
// Kernel 0: wprep (64 blocks): Wt_hi[c][k] = bf16(W[k][c]) transpose, plus
// u_src/u_dst GEMV: Ub[head][vec][k] = sum_d W[k, head*64+d] * a_vec[head,d].
// ---------------------------------------------------------------------------
__global__ __launch_bounds__(256) void wprep_kernel(const float* __restrict__ W,
                                                    const float* __restrict__ a_src,
                                                    const float* __restrict__ a_dst,
                                                    ushort* __restrict__ Wt_hi,
                                                    float* __restrict__ Ub) {
    const int t = threadIdx.x, blk = blockIdx.x;
    const int wid = t >> 6, lane = t & 63;
    float v[4];
    #pragma unroll
    for (int kk = 0; kk < 4; kk++) v[kk] = W[(blk * 4 + kk) * 256 + t];
    uint h0 = cvt_pk_bf16(v[0], v[1]);
    uint h1 = cvt_pk_bf16(v[2], v[3]);
    *(uint2*)&Wt_hi[(size_t)t * 256 + blk * 4] = make_uint2(h0, h1);

    // u GEMV: column c = t belongs to head t>>6 == wid (wave-aligned).
    const float as = a_src[t], ad = a_dst[t];
    float ps[4], pd[4];
    #pragma unroll
    for (int kk = 0; kk < 4; kk++) { ps[kk] = v[kk] * as; pd[kk] = v[kk] * ad; }
    #pragma unroll
    for (int off = 1; off < 64; off <<= 1)
        #pragma unroll
        for (int kk = 0; kk < 4; kk++) {
            ps[kk] += __shfl_xor(ps[kk], off);
            pd[kk] += __shfl_xor(pd[kk], off);
        }
    if (lane == 0) {
        #pragma unroll
        for (int kk = 0; kk < 4; kk++) {
            Ub[wid * 512 + blk * 4 + kk]       = ps[kk];
            Ub[wid * 512 + 256 + blk * 4 + kk] = pd[kk];
        }
    }
}

// ---------------------------------------------------------------------------
// Kernel 1: fused GEMM + exact-f32 scores. R5: ALL 4 heads per block so h is
// read ONCE (16 MB total, was 64 MB). Grid (512) x 256 thr, 2 blocks/CU.
// Block: 32 m x 256 c. Wave w: rows (w&1)*16, col-half (w>>1)*128 (2 heads),
// 8 frags. B staged per k-half (256c x 128k, 69.6 KB), restaged once
// (Wt_hi is 128 KB L2-resident; restage is free HBM-wise).
// ---------------------------------------------------------------------------
#define BP2 136  // B LDS pitch (ushorts) = 68 dwords === 4 mod 32 (as before)
#define EP2 40   // epilogue LDS pitch (ushorts)

__global__ __launch_bounds__(256, 2) void gemm_fused(const float* __restrict__ h,
                                                     const ushort* __restrict__ Wt_hi,
                                                     const float* __restrict__ Ub,
                                                     ushort* __restrict__ Wht,
                                                     float* __restrict__ Ee,
                                                     float* __restrict__ Ff,
                                                     float* __restrict__ Gg) {
    __shared__ ushort Bs[256 * BP2];           // 69.6 KB
    __shared__ float us[1024], ud[1024];       // 8 KB (us[head*256 + k])

    const int t = threadIdx.x;
    const int m0 = blockIdx.x * 32;
    const int b  = m0 >> 11;
    const int w = t >> 6, lane = t & 63;
    const int wm = w & 1, wc = w >> 1;
    const int c16 = lane & 15, quad = lane >> 4;
    const int hd0 = wc * 2, hd1 = hd0 + 1;
    const int qrot = ((t >> 3) & 7) * 2;       // stage-order rotation (bank spread)

    // ---- stage u (all heads) ----
    #pragma unroll
    for (int i = 0; i < 4; i++) {
        us[i * 256 + t] = Ub[i * 512 + t];
        ud[i * 256 + t] = Ub[i * 512 + 256 + t];
    }
    // ---- stage B k-half 0: thread t = c-row, 128 ushorts ----
    {
        const ushort* src = Wt_hi + (size_t)t * 256;
        ushort* dst = Bs + t * BP2;
        #pragma unroll
        for (int q = 0; q < 16; q++) {
            const int qq = (q + qrot) & 15;
            *(uint4*)(dst + qq * 8) = *(const uint4*)(src + qq * 8);
        }
    }

    const int row0 = m0 + wm * 16 + c16;
    const float* hp0 = h + (size_t)row0 * 256 + quad * 8;
    float4 p0a = *(const float4*)hp0, p0b = *(const float4*)(hp0 + 4);

    __syncthreads();                            // B + u staged

    f32x4 acc[8] = {};
    float s0 = 0.f, d0 = 0.f, s1 = 0.f, d1 = 0.f;
    for (int kh = 0; kh < 2; kh++) {
        if (kh) {                               // restage B k-half 1
            __syncthreads();
            const ushort* src = Wt_hi + (size_t)t * 256 + 128;
            ushort* dst = Bs + t * BP2;
            #pragma unroll
            for (int q = 0; q < 16; q++) {
                const int qq = (q + qrot) & 15;
                *(uint4*)(dst + qq * 8) = *(const uint4*)(src + qq * 8);
            }
            __syncthreads();
        }
        #pragma unroll
        for (int kk = 0; kk < 128; kk += 32) {
            const int k0 = kh * 128 + kk;
            float v0[8] = {p0a.x, p0a.y, p0a.z, p0a.w, p0b.x, p0b.y, p0b.z, p0b.w};
            if (k0 < 224) {                     // prefetch next k-slice
                p0a = *(const float4*)(hp0 + k0 + 32);
                p0b = *(const float4*)(hp0 + k0 + 36);
            }
            // exact-f32 score GEMV for this wave's 2 heads
            {
                float4 ua0 = *(const float4*)&us[hd0 * 256 + k0 + quad * 8];
                float4 ua1 = *(const float4*)&us[hd0 * 256 + k0 + quad * 8 + 4];
                float4 ub0 = *(const float4*)&us[hd1 * 256 + k0 + quad * 8];
                float4 ub1 = *(const float4*)&us[hd1 * 256 + k0 + quad * 8 + 4];
                float4 wa0 = *(const float4*)&ud[hd0 * 256 + k0 + quad * 8];
                float4 wa1 = *(const float4*)&ud[hd0 * 256 + k0 + quad * 8 + 4];
                float4 wb0 = *(const float4*)&ud[hd1 * 256 + k0 + quad * 8];
                float4 wb1 = *(const float4*)&ud[hd1 * 256 + k0 + quad * 8 + 4];
                s0 += v0[0]*ua0.x + v0[1]*ua0.y + v0[2]*ua0.z + v0[3]*ua0.w
                    + v0[4]*ua1.x + v0[5]*ua1.y + v0[6]*ua1.z + v0[7]*ua1.w;
                s1 += v0[0]*ub0.x + v0[1]*ub0.y + v0[2]*ub0.z + v0[3]*ub0.w
                    + v0[4]*ub1.x + v0[5]*ub1.y + v0[6]*ub1.z + v0[7]*ub1.w;
                d0 += v0[0]*wa0.x + v0[1]*wa0.y + v0[2]*wa0.z + v0[3]*wa0.w
                    + v0[4]*wa1.x + v0[5]*wa1.y + v0[6]*wa1.z + v0[7]*wa1.w;
                d1 += v0[0]*wb0.x + v0[1]*wb0.y + v0[2]*wb0.z + v0[3]*wb0.w
                    + v0[4]*wb1.x + v0[5]*wb1.y + v0[6]*wb1.z + v0[7]*wb1.w;
            }
            bf16x8 ah = cast8(v0);
            #pragma unroll
            for (int fc = 0; fc < 8; fc++) {
                bf16x8 bhf = *(const bf16x8*)&Bs[(wc * 128 + fc * 16 + c16) * BP2 + kk + quad * 8];
                acc[fc] = __builtin_amdgcn_mfma_f32_16x16x32_bf16(ah, bhf, acc[fc], 0, 0, 0);
            }
        }
    }

    // ---- scores epilogue: reduce GEMV partials over quad (k-coverage) ----
    {
        #pragma unroll
        for (int off = 16; off < 64; off <<= 1) {
            s0 += __shfl_xor(s0, off); d0 += __shfl_xor(d0, off);
            s1 += __shfl_xor(s1, off); d1 += __shfl_xor(d1, off);
        }
        if (quad == 0) {
            const int mloc = row0 & 2047;
            {
                float ee = s0 * LOG2E, rr = d0 * LOG2E;
                int idx = (b * 4 + hd0) * N_ + mloc;
                Ee[idx] = __builtin_amdgcn_exp2f(rr);
                Ff[idx] = __builtin_amdgcn_exp2f(NEG * rr);
                Gg[idx] = __builtin_amdgcn_exp2f(-0.8f * ee);
            }
            {
                float ee = s1 * LOG2E, rr = d1 * LOG2E;
                int idx = (b * 4 + hd1) * N_ + mloc;
                Ee[idx] = __builtin_amdgcn_exp2f(rr);
                Ff[idx] = __builtin_amdgcn_exp2f(NEG * rr);
                Gg[idx] = __builtin_amdgcn_exp2f(-0.8f * ee);
            }
        }
    }

    // ---- Wht epilogue: transpose via LDS (reuse Bs), coalesced stores ----
    __syncthreads();
    ushort* Es = Bs;
    {
        const int nloc = wm * 16 + quad * 4;
        #pragma unroll
        for (int fc = 0; fc < 8; fc++) {
            const int d = wc * 128 + fc * 16 + c16;
            uint2 pk = make_uint2(cvt_pk_bf16(acc[fc][0], acc[fc][1]),
                                  cvt_pk_bf16(acc[fc][2], acc[fc][3]));
            *(uint2*)&Es[d * EP2 + nloc] = pk;
        }
    }
    __syncthreads();
    {
        const int d = t;                        // global c index 0..255
        ushort* dst = Wht + ((size_t)(b * 4 + (d >> 6)) * 64 + (d & 63)) * N_ + (m0 & 2047);
        const ushort* srcl = &Es[d * EP2];
        #pragma unroll
        for (int q = 0; q < 4; q++)
            *(uint4*)(dst + q * 8) = *(const uint4*)(srcl + q * 8);
    }
}

// ---------------------------------------------------------------------------
// Kernel 2: attention. q_ij = max(E_j, G_i*F_j) (normalization-free; per-i
// scale cancels in acc/den). Grid (bh=32, itile=16): XCD = bh%8 L2 locality.
// Block = 256 thr, 4 waves x 32 i (g=2) = 128 i. 128-j tiles, double-buffered.
// den via VALU on f32 q (frees the ones-MFMA); no setprio (lockstep block).
// ---------------------------------------------------------------------------
#define TP2 144  // pitch (ushorts) = 72 dwords === 8 mod 32 (conflict-free)

__global__ __launch_bounds__(256, 2) void attn_kernel(const ushort* __restrict__ Wht,
                                                      const float* __restrict__ Ee,
                                                      const float* __restrict__ Ff,
                                                      const float* __restrict__ Gg,
                                                      const float* __restrict__ bias,
                                                      float* __restrict__ out) {
    __shared__ ushort Whs[2][64 * TP2];
    __shared__ float E_s[2][128], F_s[2][128];
    const int t = threadIdx.x;
    const int bh = blockIdx.x, b = bh >> 2, hh = bh & 3;
    const int wid = t >> 6, lane = t & 63;
    const int c16 = lane & 15, quad = lane >> 4;
    const int ibase = blockIdx.y * 128 + wid * 32;
    const int sd = t >> 3, sch = t & 7;   // staging: rows sd / sd+32, chunks sch / sch+8

    float Gi[2];
    #pragma unroll
    for (int g = 0; g < 2; g++) Gi[g] = Gg[bh * N_ + ibase + g * 16 + c16];

    f32x4 acc[2][4] = {};
    float dsa[2] = {0.f, 0.f}, dsb[2] = {0.f, 0.f};  // den partials (rows g*16+c16)
    const ushort* WhtB = Wht + (size_t)bh * 64 * N_;
    const float* Eb = Ee + (size_t)bh * N_;
    const float* Fb = Ff + (size_t)bh * N_;

    // prefetch tile 0
    uint4 w00 = *(const uint4*)(WhtB + (size_t)sd * N_ + sch * 8);
    uint4 w01 = *(const uint4*)(WhtB + (size_t)sd * N_ + 64 + sch * 8);
    uint4 w10 = *(const uint4*)(WhtB + (size_t)(sd + 32) * N_ + sch * 8);
    uint4 w11 = *(const uint4*)(WhtB + (size_t)(sd + 32) * N_ + 64 + sch * 8);
    float ev_e = 0.f, ev_f = 0.f;
    if (t < 128) { ev_e = Eb[t]; ev_f = Fb[t]; }

    for (int jt = 0; jt < 16; jt++) {
        const int buf = jt & 1;
        *(uint4*)&Whs[buf][sd * TP2 + sch * 8]             = w00;
        *(uint4*)&Whs[buf][sd * TP2 + 64 + sch * 8]        = w01;
        *(uint4*)&Whs[buf][(sd + 32) * TP2 + sch * 8]      = w10;
        *(uint4*)&Whs[buf][(sd + 32) * TP2 + 64 + sch * 8] = w11;
        if (t < 128) { E_s[buf][t] = ev_e; F_s[buf][t] = ev_f; }
        if (jt < 15) {                          // prefetch next tile
            const int j1 = (jt + 1) * 128;
            w00 = *(const uint4*)(WhtB + (size_t)sd * N_ + j1 + sch * 8);
            w01 = *(const uint4*)(WhtB + (size_t)sd * N_ + j1 + 64 + sch * 8);
            w10 = *(const uint4*)(WhtB + (size_t)(sd + 32) * N_ + j1 + sch * 8);
            w11 = *(const uint4*)(WhtB + (size_t)(sd + 32) * N_ + j1 + 64 + sch * 8);
            if (t < 128) { ev_e = Eb[j1 + t]; ev_f = Fb[j1 + t]; }
        }
        __syncthreads();                        // tile[buf] ready
        #pragma unroll
        for (int ks = 0; ks < 4; ks++) {
            const int jb = ks * 32 + quad * 8;
            float4 e0 = *(const float4*)&E_s[buf][jb];
            float4 e1 = *(const float4*)&E_s[buf][jb + 4];
            float4 f0 = *(const float4*)&F_s[buf][jb];
            float4 f1 = *(const float4*)&F_s[buf][jb + 4];
            float E8[8] = {e0.x, e0.y, e0.z, e0.w, e1.x, e1.y, e1.z, e1.w};
            float F8[8] = {f0.x, f0.y, f0.z, f0.w, f1.x, f1.y, f1.z, f1.w};
            bf16x8 bfr[4];
            #pragma unroll
            for (int fd = 0; fd < 4; fd++)
                bfr[fd] = *(const bf16x8*)&Whs[buf][(fd * 16 + c16) * TP2 + jb];
            #pragma unroll
            for (int g = 0; g < 2; g++) {
                const float gi = Gi[g];
                union { bf16x8 v; uint u[4]; } af;
                float da = 0.f, db = 0.f;       // paired den accumulation
                #pragma unroll
                for (int j = 0; j < 4; j++) {
                    float qa = fmaxf(E8[2 * j],     gi * F8[2 * j]);
                    float qb = fmaxf(E8[2 * j + 1], gi * F8[2 * j + 1]);
                    da += qa; db += qb;
                    af.u[j] = cvt_pk_bf16(qa, qb);
                }
                dsa[g] += da; dsb[g] += db;
                #pragma unroll
                for (int fd = 0; fd < 4; fd++)
                    acc[g][fd] = __builtin_amdgcn_mfma_f32_16x16x32_bf16(af.v, bfr[fd], acc[g][fd], 0, 0, 0);
            }
        }
    }

    // ---- den: finish per-row sums, reduce over quad (j-coverage) ----
    float den[2];
    #pragma unroll
    for (int g = 0; g < 2; g++) {
        float d = dsa[g] + dsb[g];
        d += __shfl_xor(d, 16);
        d += __shfl_xor(d, 32);                 // row g*16+c16 full den, all quads
        den[g] = d;
    }

    float bl[4];
    #pragma unroll
    for (int fd = 0; fd < 4; fd++) bl[fd] = bias[hh * 64 + fd * 16 + c16];
    #pragma unroll
    for (int g = 0; g < 2; g++)
        #pragma unroll
        for (int r = 0; r < 4; r++) {
            int i = ibase + g * 16 + quad * 4 + r;
            float dv = __shfl(den[g], quad * 4 + r);   // row quad*4+r lives at lane c16==quad*4+r
            float inv = 1.0f / dv;
            float* dst = out + (size_t)(b * N_ + i) * C_ + hh * 64;
            #pragma unroll
            for (int fd = 0; fd < 4; fd++)
                dst[fd * 16 + c16] = acc[g][fd][r] * inv + bl[fd];
        }
}

// ---------------------------------------------------------------------------
extern "C" void kernel_launch(void* const* d_in, const int* in_sizes, int n_in,
                              void* d_out, int out_size, void* d_ws, size_t ws_size,
                              hipStream_t stream) {
    const float* h     = (const float*)d_in[0];
    const float* W     = (const float*)d_in[1];
    const float* a_src = (const float*)d_in[2];
    const float* a_dst = (const float*)d_in[3];
    const float* bias  = (const float*)d_in[4];
    float* out = (float*)d_out;

    ushort* Wt_hi = (ushort*)d_ws;                       // 256*256 ushorts
    float*  Ub    = (float*)(Wt_hi + 256 * 256);         // 4 heads * 512 f32
    ushort* Wht   = (ushort*)(Ub + 4 * 512);             // M_*C_ bf16 [bh][d][n]
    float*  Ee    = (float*)(Wht + (size_t)M_ * C_);     // 32*2048
    float*  Ff    = Ee + 32 * N_;
    float*  Gg    = Ff + 32 * N_;

    wprep_kernel<<<64, 256, 0, stream>>>(W, a_src, a_dst, Wt_hi, Ub);
    gemm_fused<<<dim3(M_ / 32), 256, 0, stream>>>(h, Wt_hi, Ub, Wht, Ee, Ff, Gg);
    attn_kernel<<<dim3(32, 16), 256, 0, stream>>>(Wht, Ee, Ff, Gg, bias, out);
}

// Round 6
// 116.092 us; speedup vs baseline: 1.0580x; 1.0580x over previous
//
#include <hip/hip_runtime.h>
#include <math.h>

#define B_   8
#define N_   2048
#define IN_  256
#define H_   4
#define D_   64
#define C_   256            // H_*D_
#define M_   (B_*N_)        // 16384
#define NEG  0.2f
#define LOG2E 1.4426950408889634f

typedef short bf16x8 __attribute__((ext_vector_type(8)));
typedef float f32x4  __attribute__((ext_vector_type(4)));

// gfx950 packed f32->bf16 (RNE), src0 -> low half, src1 -> high half.
__device__ inline uint cvt_pk_bf16(float lo, float hi) {
    uint r;
    asm("v_cvt_pk_bf16_f32 %0, %1, %2" : "=v"(r) : "v"(lo), "v"(hi));
    return r;
}

// split 8 f32 -> hi/lo bf16x8 via cvt_pk.
__device__ inline void split8(const float v[8], bf16x8* hi, bf16x8* lo) {
    union { bf16x8 v; uint u[4]; } H, L;
    #pragma unroll
    for (int j = 0; j < 4; j++) {
        float a = v[2 * j], b = v[2 * j + 1];
        uint ph = cvt_pk_bf16(a, b);
        float ra = a - __uint_as_float(ph << 16);
        float rb = b - __uint_as_float(ph & 0xFFFF0000u);
        H.u[j] = ph;
        L.u[j] = cvt_pk_bf16(ra, rb);
    }
    *hi = H.v; *lo = L.v;
}

// ---------------------------------------------------------------------------
// Kernel 0: wprep (64 blocks): Wt_hi[c][k] = bf16(W[k][c]) transpose, plus
// u_src/u_dst GEMV: Ub[head][vec][k] = sum_d W[k, head*64+d] * a_vec[head,d].
// Each wave (64 lanes) covers exactly one head's column range -> wave reduce.
// ---------------------------------------------------------------------------
__global__ __launch_bounds__(256) void wprep_kernel(const float* __restrict__ W,
                                                    const float* __restrict__ a_src,
                                                    const float* __restrict__ a_dst,
                                                    ushort* __restrict__ Wt_hi,
                                                    float* __restrict__ Ub) {
    const int t = threadIdx.x, blk = blockIdx.x;
    const int wid = t >> 6, lane = t & 63;
    float v[4];
    #pragma unroll
    for (int kk = 0; kk < 4; kk++) v[kk] = W[(blk * 4 + kk) * 256 + t];
    uint h0 = cvt_pk_bf16(v[0], v[1]);
    uint h1 = cvt_pk_bf16(v[2], v[3]);
    *(uint2*)&Wt_hi[(size_t)t * 256 + blk * 4] = make_uint2(h0, h1);

    // u GEMV: column c = t belongs to head t>>6 == wid (wave-aligned).
    const float as = a_src[t], ad = a_dst[t];
    float ps[4], pd[4];
    #pragma unroll
    for (int kk = 0; kk < 4; kk++) { ps[kk] = v[kk] * as; pd[kk] = v[kk] * ad; }
    #pragma unroll
    for (int off = 1; off < 64; off <<= 1)
        #pragma unroll
        for (int kk = 0; kk < 4; kk++) {
            ps[kk] += __shfl_xor(ps[kk], off);
            pd[kk] += __shfl_xor(pd[kk], off);
        }
    if (lane == 0) {
        #pragma unroll
        for (int kk = 0; kk < 4; kk++) {
            Ub[wid * 512 + blk * 4 + kk]       = ps[kk];
            Ub[wid * 512 + 256 + blk * 4 + kk] = pd[kk];
        }
    }
}

// ---------------------------------------------------------------------------
// Kernel 1: fused GEMM + exact-f32 scores via u-GEMV.  (R2 best config)
// Grid (256, 4) = 1024 blocks x 256 thr, 4 blocks/CU (35.8 KB LDS).
// Block: 64 m x 64 c (1 head). 2 MFMA/frag (A hi+lo, B hi only).
// Scores: el/er = h . u_vec accumulated in f32 registers during the K-loop.
// ---------------------------------------------------------------------------
#define BP 264   // B LDS pitch (ushorts)
#define EP 74    // epilogue LDS pitch (ushorts)

__global__ __launch_bounds__(256, 4) void gemm_fused(const float* __restrict__ h,
                                                     const ushort* __restrict__ Wt_hi,
                                                     const float* __restrict__ Ub,
                                                     ushort* __restrict__ Wht,
                                                     float* __restrict__ Ee,
                                                     float* __restrict__ Ff,
                                                     float* __restrict__ Gg) {
    __shared__ ushort Bs_h[64 * BP];
    __shared__ float us[256], ud[256];

    const int t = threadIdx.x;
    const int m0 = blockIdx.x * 64;
    const int nb = blockIdx.y;                 // head
    const int b  = m0 >> 11;
    const int wid = t >> 6, lane = t & 63;
    const int c16 = lane & 15, quad = lane >> 4;

    // ---- stage B (hi only): thread = (c = t>>2, k-quarter = t&3) ----
    {
        const int c = t >> 2, kq = t & 3;
        const ushort* sh = Wt_hi + (size_t)(nb * 64 + c) * 256 + kq * 64;
        ushort* dh = &Bs_h[c * BP + kq * 64];
        #pragma unroll
        for (int q = 0; q < 8; q++)
            *(uint4*)(dh + q * 8) = *(const uint4*)(sh + q * 8);
    }
    us[t] = Ub[nb * 512 + t];
    ud[t] = Ub[nb * 512 + 256 + t];

    const int row0 = m0 + wid * 16 + c16;
    const float* hp0 = h + (size_t)row0 * 256 + quad * 8;

    // prefetch A slice 0 (f32)
    float4 p0a = *(const float4*)hp0, p0b = *(const float4*)(hp0 + 4);

    __syncthreads();                            // B + u staged

    f32x4 acc[4] = {};
    float ds = 0.f, dd = 0.f;
    for (int k0 = 0; k0 < 256; k0 += 32) {
        float v0[8] = {p0a.x, p0a.y, p0a.z, p0a.w, p0b.x, p0b.y, p0b.z, p0b.w};
        if (k0 < 224) {                         // prefetch next slice
            p0a = *(const float4*)(hp0 + k0 + 32); p0b = *(const float4*)(hp0 + k0 + 36);
        }
        // exact-f32 score GEMV (u broadcast reads, conflict-free)
        {
            float4 u0 = *(const float4*)&us[k0 + quad * 8];
            float4 u1 = *(const float4*)&us[k0 + quad * 8 + 4];
            float4 w0 = *(const float4*)&ud[k0 + quad * 8];
            float4 w1 = *(const float4*)&ud[k0 + quad * 8 + 4];
            ds += v0[0]*u0.x + v0[1]*u0.y + v0[2]*u0.z + v0[3]*u0.w
                + v0[4]*u1.x + v0[5]*u1.y + v0[6]*u1.z + v0[7]*u1.w;
            dd += v0[0]*w0.x + v0[1]*w0.y + v0[2]*w0.z + v0[3]*w0.w
                + v0[4]*w1.x + v0[5]*w1.y + v0[6]*w1.z + v0[7]*w1.w;
        }
        bf16x8 ah, al;
        split8(v0, &ah, &al);
        #pragma unroll
        for (int fc = 0; fc < 4; fc++) {
            bf16x8 bhf = *(const bf16x8*)&Bs_h[(fc * 16 + c16) * BP + k0 + quad * 8];
            acc[fc] = __builtin_amdgcn_mfma_f32_16x16x32_bf16(ah, bhf, acc[fc], 0, 0, 0);
            acc[fc] = __builtin_amdgcn_mfma_f32_16x16x32_bf16(al, bhf, acc[fc], 0, 0, 0);
        }
    }

    // ---- scores epilogue: reduce GEMV partials over quad (k-coverage) ----
    {
        #pragma unroll
        for (int off = 16; off < 64; off <<= 1) {
            ds += __shfl_xor(ds, off);
            dd += __shfl_xor(dd, off);
        }
        if (quad == 0) {
            int m = m0 + wid * 16 + c16;
            int idx = (b * 4 + nb) * N_ + (m & 2047);
            float ee = ds * LOG2E;              // el (log2-domain)
            float rr = dd * LOG2E;              // er (log2-domain)
            Ee[idx] = __builtin_amdgcn_exp2f(rr);
            Ff[idx] = __builtin_amdgcn_exp2f(NEG * rr);
            Gg[idx] = __builtin_amdgcn_exp2f(-0.8f * ee);
        }
    }

    // ---- Wht epilogue: transpose via LDS (reuse Bs_h), coalesced stores ----
    __syncthreads();
    ushort* Es = Bs_h;
    {
        const int nloc = wid * 16 + quad * 4;
        #pragma unroll
        for (int fc = 0; fc < 4; fc++) {
            const int d = fc * 16 + c16;
            uint2 pk = make_uint2(cvt_pk_bf16(acc[fc][0], acc[fc][1]),
                                  cvt_pk_bf16(acc[fc][2], acc[fc][3]));
            *(uint2*)&Es[d * EP + nloc] = pk;
        }
    }
    __syncthreads();
    {
        const int d = t >> 2, ch = t & 3;
        ushort* dst = Wht + ((size_t)(b * 4 + nb) * 64 + d) * N_ + (m0 & 2047) + ch * 16;
        const ushort* srcl = &Es[d * EP + ch * 16];
        *(uint4*)(dst)     = *(const uint4*)(srcl);
        *(uint4*)(dst + 8) = *(const uint4*)(srcl + 8);
    }
}

// ---------------------------------------------------------------------------
// Kernel 2: attention. q_ij = max(E_j, G_i*F_j) (normalization-free; per-i
// scale cancels in acc/den). Grid (bh=32, itile=16): XCD = bh%8 L2 locality.
// Block = 256 thr, 4 waves x 32 i (g=2) = 128 i. 128-j tiles, double-buffered.
// ---------------------------------------------------------------------------
#define TP2 144  // pitch (ushorts) = 72 dwords === 8 mod 32 (conflict-free)

__global__ __launch_bounds__(256, 2) void attn_kernel(const ushort* __restrict__ Wht,
                                                      const float* __restrict__ Ee,
                                                      const float* __restrict__ Ff,
                                                      const float* __restrict__ Gg,
                                                      const float* __restrict__ bias,
                                                      float* __restrict__ out) {
    __shared__ ushort Whs[2][64 * TP2];
    __shared__ float E_s[2][128], F_s[2][128];
    const int t = threadIdx.x;
    const int bh = blockIdx.x, b = bh >> 2, hh = bh & 3;
    const int wid = t >> 6, lane = t & 63;
    const int c16 = lane & 15, quad = lane >> 4;
    const int ibase = blockIdx.y * 128 + wid * 32;
    const int sd = t >> 3, sch = t & 7;   // staging: rows sd / sd+32, chunks sch / sch+8

    float Gi[2];
    #pragma unroll
    for (int g = 0; g < 2; g++) Gi[g] = Gg[bh * N_ + ibase + g * 16 + c16];

    f32x4 acc[2][4] = {};
    f32x4 den[2] = {};
    const bf16x8 ones = {0x3F80, 0x3F80, 0x3F80, 0x3F80,
                         0x3F80, 0x3F80, 0x3F80, 0x3F80};
    const ushort* WhtB = Wht + (size_t)bh * 64 * N_;
    const float* Eb = Ee + (size_t)bh * N_;
    const float* Fb = Ff + (size_t)bh * N_;

    // prefetch tile 0
    uint4 w00 = *(const uint4*)(WhtB + (size_t)sd * N_ + sch * 8);
    uint4 w01 = *(const uint4*)(WhtB + (size_t)sd * N_ + 64 + sch * 8);
    uint4 w10 = *(const uint4*)(WhtB + (size_t)(sd + 32) * N_ + sch * 8);
    uint4 w11 = *(const uint4*)(WhtB + (size_t)(sd + 32) * N_ + 64 + sch * 8);
    float ev_e = 0.f, ev_f = 0.f;
    if (t < 128) { ev_e = Eb[t]; ev_f = Fb[t]; }

    for (int jt = 0; jt < 16; jt++) {
        const int buf = jt & 1;
        *(uint4*)&Whs[buf][sd * TP2 + sch * 8]             = w00;
        *(uint4*)&Whs[buf][sd * TP2 + 64 + sch * 8]        = w01;
        *(uint4*)&Whs[buf][(sd + 32) * TP2 + sch * 8]      = w10;
        *(uint4*)&Whs[buf][(sd + 32) * TP2 + 64 + sch * 8] = w11;
        if (t < 128) { E_s[buf][t] = ev_e; F_s[buf][t] = ev_f; }
        if (jt < 15) {                          // prefetch next tile
            const int j1 = (jt + 1) * 128;
            w00 = *(const uint4*)(WhtB + (size_t)sd * N_ + j1 + sch * 8);
            w01 = *(const uint4*)(WhtB + (size_t)sd * N_ + j1 + 64 + sch * 8);
            w10 = *(const uint4*)(WhtB + (size_t)(sd + 32) * N_ + j1 + sch * 8);
            w11 = *(const uint4*)(WhtB + (size_t)(sd + 32) * N_ + j1 + 64 + sch * 8);
            if (t < 128) { ev_e = Eb[j1 + t]; ev_f = Fb[j1 + t]; }
        }
        __syncthreads();                        // tile[buf] ready
        #pragma unroll
        for (int ks = 0; ks < 4; ks++) {
            const int jb = ks * 32 + quad * 8;
            float4 e0 = *(const float4*)&E_s[buf][jb];
            float4 e1 = *(const float4*)&E_s[buf][jb + 4];
            float4 f0 = *(const float4*)&F_s[buf][jb];
            float4 f1 = *(const float4*)&F_s[buf][jb + 4];
            float E8[8] = {e0.x, e0.y, e0.z, e0.w, e1.x, e1.y, e1.z, e1.w};
            float F8[8] = {f0.x, f0.y, f0.z, f0.w, f1.x, f1.y, f1.z, f1.w};
            bf16x8 bfr[4];
            #pragma unroll
            for (int fd = 0; fd < 4; fd++)
                bfr[fd] = *(const bf16x8*)&Whs[buf][(fd * 16 + c16) * TP2 + jb];
            #pragma unroll
            for (int g = 0; g < 2; g++) {
                const float gi = Gi[g];
                union { bf16x8 v; uint u[4]; } af;
                #pragma unroll
                for (int j = 0; j < 4; j++) {
                    float qa = fmaxf(E8[2 * j],     gi * F8[2 * j]);
                    float qb = fmaxf(E8[2 * j + 1], gi * F8[2 * j + 1]);
                    af.u[j] = cvt_pk_bf16(qa, qb);
                }
                #pragma unroll
                for (int fd = 0; fd < 4; fd++)
                    acc[g][fd] = __builtin_amdgcn_mfma_f32_16x16x32_bf16(af.v, bfr[fd], acc[g][fd], 0, 0, 0);
                den[g] = __builtin_amdgcn_mfma_f32_16x16x32_bf16(af.v, ones, den[g], 0, 0, 0);
            }
        }
    }

    float bl[4];
    #pragma unroll
    for (int fd = 0; fd < 4; fd++) bl[fd] = bias[hh * 64 + fd * 16 + c16];
    #pragma unroll
    for (int g = 0; g < 2; g++)
        #pragma unroll
        for (int r = 0; r < 4; r++) {
            int i = ibase + g * 16 + quad * 4 + r;
            float inv = 1.0f / den[g][r];
            float* dst = out + (size_t)(b * N_ + i) * C_ + hh * 64;
            #pragma unroll
            for (int fd = 0; fd < 4; fd++)
                dst[fd * 16 + c16] = acc[g][fd][r] * inv + bl[fd];
        }
}

// ---------------------------------------------------------------------------
extern "C" void kernel_launch(void* const* d_in, const int* in_sizes, int n_in,
                              void* d_out, int out_size, void* d_ws, size_t ws_size,
                              hipStream_t stream) {
    const float* h     = (const float*)d_in[0];
    const float* W     = (const float*)d_in[1];
    const float* a_src = (const float*)d_in[2];
    const float* a_dst = (const float*)d_in[3];
    const float* bias  = (const float*)d_in[4];
    float* out = (float*)d_out;

    ushort* Wt_hi = (ushort*)d_ws;                       // 256*256 ushorts
    float*  Ub    = (float*)(Wt_hi + 256 * 256);         // 4 heads * 512 f32
    ushort* Wht   = (ushort*)(Ub + 4 * 512);             // M_*C_ bf16 [bh][d][n]
    float*  Ee    = (float*)(Wht + (size_t)M_ * C_);     // 32*2048
    float*  Ff    = Ee + 32 * N_;
    float*  Gg    = Ff + 32 * N_;

    wprep_kernel<<<64, 256, 0, stream>>>(W, a_src, a_dst, Wt_hi, Ub);
    gemm_fused<<<dim3(M_ / 64, 4), 256, 0, stream>>>(h, Wt_hi, Ub, Wht, Ee, Ff, Gg);
    attn_kernel<<<dim3(32, 16), 256, 0, stream>>>(Wht, Ee, Ff, Gg, bias, out);
}